// Round 8
// baseline (104.710 us; speedup 1.0000x reference)
//
#include <hip/hip_runtime.h>
#include <math.h>

#define BB 8
#define SS 8192
#define DD 64
#define DM 1024
#define EPSF 1e-8f
#define NROWS (BB * SS)                 // 65536 rows
#define YQ_ELEMS ((size_t)NROWS * DM)   // yQ elements; xi follows in d_out

#define NPBLK 64                        // P-blocks inside kernel 1
#define XROWS 64                        // rows per xi-block (16 per wave)
#define SROWS 64                        // rows per stream-block

typedef float floatx4 __attribute__((ext_vector_type(4)));

#define SUM4(a) ((a).x + (a).y + (a).z + (a).w)
#define DOT4(a) ((a).x * (a).x + (a).y * (a).y + (a).z * (a).z + (a).w * (a).w)

// ws float layout (final vectors, 16 KB):
//   UP[1024] | UN[1024] | CP[1024]=b2+DP | CN[1024]=b2+DN

// ---------------- Kernel 1: P-blocks (0..63) + xi-blocks ----------------
__global__ __launch_bounds__(256) void qac_prep(
    const float* __restrict__ psiQ, const float* __restrict__ psiK,
    const float* __restrict__ psiV, const float* __restrict__ W1,
    const float* __restrict__ b1, const float* __restrict__ W2,
    const float* __restrict__ b2, float* __restrict__ ws,
    float* __restrict__ out) {
  const int t = threadIdx.x;

  if (blockIdx.x < NPBLK) {
    // ---- P: final per-n vectors for 16 columns ----
    __shared__ float red[4][16][16];
    const int tn = t & 15;
    const int tm = t >> 4;
    const int nb = blockIdx.x;
    const int n = nb * 16 + tn;

    float up = 0.f, un = 0.f, dp = 0.f, dn = 0.f;
    const int m0 = tm * 64;
#pragma unroll 8
    for (int i = 0; i < 64; ++i) {
      const int m = m0 + i;
      const float w1 = W1[m];
      const float bv = b1[m];
      const float w2 = W2[(size_t)m * DM + n];
      const float wp = w1 > 0.f ? w1 : 0.f;
      const float wn = w1 < 0.f ? w1 : 0.f;
      const float bp = w1 > 0.f ? bv : 0.f;
      const float bn = w1 < 0.f ? bv : 0.f;
      up = fmaf(wp, w2, up);
      un = fmaf(wn, w2, un);
      dp = fmaf(bp, w2, dp);
      dn = fmaf(bn, w2, dn);
    }
    red[0][tm][tn] = up;
    red[1][tm][tn] = un;
    red[2][tm][tn] = dp;
    red[3][tm][tn] = dn;
    __syncthreads();
    if (t < 64) {
      const int q = t >> 4;
      const int col = t & 15;
      float s = 0.f;
#pragma unroll
      for (int j = 0; j < 16; ++j) s += red[q][j][col];
      const int n2 = nb * 16 + col;
      if (q < 2) {
        ws[q * DM + n2] = s;             // UP / UN
      } else {
        ws[q * DM + n2] = b2[n2] + s;    // CP / CN (b2 folded)
      }
    }
    return;
  }

  // ---- X: 64 rows/block, 4 lanes per row, 2-step shfl reduce ----
  const int wv = t >> 6;         // wave 0..3
  const int l = t & 63;
  const int g = l & 3;           // lane within 4-lane row group
  const int rw = l >> 2;         // row within wave 0..15
  const int row = (blockIdx.x - NPBLK) * XROWS + wv * 16 + rw;

  const floatx4* qp = (const floatx4*)(psiQ + (size_t)row * DD);
  const floatx4* kp = (const floatx4*)(psiK + (size_t)row * DD);
  const floatx4* vp = (const floatx4*)(psiV + (size_t)row * DD);

  floatx4 q0 = __builtin_nontemporal_load(qp + (0 * 4 + g));
  floatx4 q1 = __builtin_nontemporal_load(qp + (1 * 4 + g));
  floatx4 q2 = __builtin_nontemporal_load(qp + (2 * 4 + g));
  floatx4 q3 = __builtin_nontemporal_load(qp + (3 * 4 + g));
  floatx4 k0v = __builtin_nontemporal_load(kp + (0 * 4 + g));
  floatx4 k1 = __builtin_nontemporal_load(kp + (1 * 4 + g));
  floatx4 k2 = __builtin_nontemporal_load(kp + (2 * 4 + g));
  floatx4 k3 = __builtin_nontemporal_load(kp + (3 * 4 + g));
  floatx4 v0 = __builtin_nontemporal_load(vp + (0 * 4 + g));
  floatx4 v1 = __builtin_nontemporal_load(vp + (1 * 4 + g));
  floatx4 v2 = __builtin_nontemporal_load(vp + (2 * 4 + g));
  floatx4 v3 = __builtin_nontemporal_load(vp + (3 * 4 + g));

  float sq = SUM4(q0) + SUM4(q1) + SUM4(q2) + SUM4(q3);
  float sq2 = DOT4(q0) + DOT4(q1) + DOT4(q2) + DOT4(q3);
  float sk2 = DOT4(k0v) + DOT4(k1) + DOT4(k2) + DOT4(k3);
  float va = DOT4(v0) + DOT4(v1);   // elements 0..31
  float vb = DOT4(v2) + DOT4(v3);   // elements 32..63
  const float k0 = k0v.x;           // k[row][0] valid on g==0

#pragma unroll
  for (int m = 1; m < 4; m <<= 1) {
    sq += __shfl_xor(sq, m);
    sq2 += __shfl_xor(sq2, m);
    sk2 += __shfl_xor(sk2, m);
    va += __shfl_xor(va, m);
    vb += __shfl_xor(vb, m);
  }
  if (g == 0) {
    const float nq = sqrtf(sq2) + EPSF;
    const float nk = sqrtf(sk2) + EPSF;
    const float nv = sqrtf(va + vb) + EPSF;
    const float sqn = sq / nq;
    const float k0n = k0 / nk;
    const float att = sqn * sqn * k0n * k0n * (1.0f / 64.0f);
    const float vexp = (va - vb) / (nv * nv);
    out[YQ_ELEMS + row] = att * vexp;
  }
}

// ---------------- Kernel Y: pure yQ stream, PLAIN stores (A/B vs R7 NT) ----------------
// Grid 1024 x 256: 64 rows/block, 256 KB contiguous stores per block.
__global__ __launch_bounds__(256) void qac_stream(
    const float* __restrict__ ws, float* __restrict__ out) {
  __shared__ float xis[SROWS];
  const int t = threadIdx.x;
  const int r0 = blockIdx.x * SROWS;
  if (t < SROWS) xis[t] = out[YQ_ELEMS + r0 + t];

  const float4 up = ((const float4*)(ws))[t];
  const float4 un = ((const float4*)(ws + DM))[t];
  const float4 cp = ((const float4*)(ws + 2 * DM))[t];
  const float4 cn = ((const float4*)(ws + 3 * DM))[t];
  __syncthreads();

#pragma unroll 8
  for (int r = 0; r < SROWS; ++r) {
    const float xi = xis[r];
    const bool pos = xi > 0.f;
    float4 o;
    o.x = fmaf(xi, pos ? up.x : un.x, pos ? cp.x : cn.x);
    o.y = fmaf(xi, pos ? up.y : un.y, pos ? cp.y : cn.y);
    o.z = fmaf(xi, pos ? up.z : un.z, pos ? cp.z : cn.z);
    o.w = fmaf(xi, pos ? up.w : un.w, pos ? cp.w : cn.w);
    ((float4*)(out + (size_t)(r0 + r) * DM))[t] = o;
  }
}

extern "C" void kernel_launch(void* const* d_in, const int* in_sizes, int n_in,
                              void* d_out, int out_size, void* d_ws, size_t ws_size,
                              hipStream_t stream) {
  const float* psiQ = (const float*)d_in[0];
  const float* psiK = (const float*)d_in[1];
  const float* psiV = (const float*)d_in[2];
  const float* W1 = (const float*)d_in[3];
  const float* b1 = (const float*)d_in[4];
  const float* W2 = (const float*)d_in[5];
  const float* b2 = (const float*)d_in[6];
  float* out = (float*)d_out;
  float* ws = (float*)d_ws;

  qac_prep<<<NPBLK + NROWS / XROWS, 256, 0, stream>>>(psiQ, psiK, psiV, W1, b1,
                                                      W2, b2, ws, out);
  qac_stream<<<NROWS / SROWS, 256, 0, stream>>>(ws, out);
}

// Round 9
// 64.818 us; speedup vs baseline: 1.6155x; 1.6155x over previous
//
#include <hip/hip_runtime.h>
#include <math.h>

#define BB 8
#define SS 8192
#define DD 64
#define DM 1024
#define EPSF 1e-8f
#define NROWS (BB * SS)                 // 65536 rows
#define YQ_ELEMS ((size_t)NROWS * DM)   // yQ elements; xi follows in d_out

#define NPBLK 64                        // P-blocks inside kernel 1
#define XROWS 64                        // rows per xi-block (16 per wave)
#define SROWS 64                        // rows per stream-block

typedef float floatx4 __attribute__((ext_vector_type(4)));

#define SUM4(a) ((a).x + (a).y + (a).z + (a).w)
#define DOT4(a) ((a).x * (a).x + (a).y * (a).y + (a).z * (a).z + (a).w * (a).w)

// ws float layout (final vectors, 16 KB):
//   UP[1024] | UN[1024] | CP[1024]=b2+DP | CN[1024]=b2+DN

// ---------------- Kernel 1: P-blocks (0..63) + xi-blocks ----------------
__global__ __launch_bounds__(256) void qac_prep(
    const float* __restrict__ psiQ, const float* __restrict__ psiK,
    const float* __restrict__ psiV, const float* __restrict__ W1,
    const float* __restrict__ b1, const float* __restrict__ W2,
    const float* __restrict__ b2, float* __restrict__ ws,
    float* __restrict__ out) {
  const int t = threadIdx.x;

  if (blockIdx.x < NPBLK) {
    // ---- P: final per-n vectors for 16 columns ----
    __shared__ float red[4][16][16];
    const int tn = t & 15;
    const int tm = t >> 4;
    const int nb = blockIdx.x;
    const int n = nb * 16 + tn;

    float up = 0.f, un = 0.f, dp = 0.f, dn = 0.f;
    const int m0 = tm * 64;
#pragma unroll 8
    for (int i = 0; i < 64; ++i) {
      const int m = m0 + i;
      const float w1 = W1[m];
      const float bv = b1[m];
      const float w2 = W2[(size_t)m * DM + n];
      const float wp = w1 > 0.f ? w1 : 0.f;
      const float wn = w1 < 0.f ? w1 : 0.f;
      const float bp = w1 > 0.f ? bv : 0.f;
      const float bn = w1 < 0.f ? bv : 0.f;
      up = fmaf(wp, w2, up);
      un = fmaf(wn, w2, un);
      dp = fmaf(bp, w2, dp);
      dn = fmaf(bn, w2, dn);
    }
    red[0][tm][tn] = up;
    red[1][tm][tn] = un;
    red[2][tm][tn] = dp;
    red[3][tm][tn] = dn;
    __syncthreads();
    if (t < 64) {
      const int q = t >> 4;
      const int col = t & 15;
      float s = 0.f;
#pragma unroll
      for (int j = 0; j < 16; ++j) s += red[q][j][col];
      const int n2 = nb * 16 + col;
      if (q < 2) {
        ws[q * DM + n2] = s;             // UP / UN
      } else {
        ws[q * DM + n2] = b2[n2] + s;    // CP / CN (b2 folded)
      }
    }
    return;
  }

  // ---- X: 64 rows/block, 4 lanes per row, 2-step shfl reduce ----
  const int wv = t >> 6;         // wave 0..3
  const int l = t & 63;
  const int g = l & 3;           // lane within 4-lane row group
  const int rw = l >> 2;         // row within wave 0..15
  const int row = (blockIdx.x - NPBLK) * XROWS + wv * 16 + rw;

  const floatx4* qp = (const floatx4*)(psiQ + (size_t)row * DD);
  const floatx4* kp = (const floatx4*)(psiK + (size_t)row * DD);
  const floatx4* vp = (const floatx4*)(psiV + (size_t)row * DD);

  floatx4 q0 = __builtin_nontemporal_load(qp + (0 * 4 + g));
  floatx4 q1 = __builtin_nontemporal_load(qp + (1 * 4 + g));
  floatx4 q2 = __builtin_nontemporal_load(qp + (2 * 4 + g));
  floatx4 q3 = __builtin_nontemporal_load(qp + (3 * 4 + g));
  floatx4 k0v = __builtin_nontemporal_load(kp + (0 * 4 + g));
  floatx4 k1 = __builtin_nontemporal_load(kp + (1 * 4 + g));
  floatx4 k2 = __builtin_nontemporal_load(kp + (2 * 4 + g));
  floatx4 k3 = __builtin_nontemporal_load(kp + (3 * 4 + g));
  floatx4 v0 = __builtin_nontemporal_load(vp + (0 * 4 + g));
  floatx4 v1 = __builtin_nontemporal_load(vp + (1 * 4 + g));
  floatx4 v2 = __builtin_nontemporal_load(vp + (2 * 4 + g));
  floatx4 v3 = __builtin_nontemporal_load(vp + (3 * 4 + g));

  float sq = SUM4(q0) + SUM4(q1) + SUM4(q2) + SUM4(q3);
  float sq2 = DOT4(q0) + DOT4(q1) + DOT4(q2) + DOT4(q3);
  float sk2 = DOT4(k0v) + DOT4(k1) + DOT4(k2) + DOT4(k3);
  float va = DOT4(v0) + DOT4(v1);   // elements 0..31
  float vb = DOT4(v2) + DOT4(v3);   // elements 32..63
  const float k0 = k0v.x;           // k[row][0] valid on g==0

#pragma unroll
  for (int m = 1; m < 4; m <<= 1) {
    sq += __shfl_xor(sq, m);
    sq2 += __shfl_xor(sq2, m);
    sk2 += __shfl_xor(sk2, m);
    va += __shfl_xor(va, m);
    vb += __shfl_xor(vb, m);
  }
  if (g == 0) {
    const float nq = sqrtf(sq2) + EPSF;
    const float nk = sqrtf(sk2) + EPSF;
    const float nv = sqrtf(va + vb) + EPSF;
    const float sqn = sq / nq;
    const float k0n = k0 / nk;
    const float att = sqn * sqn * k0n * k0n * (1.0f / 64.0f);
    const float vexp = (va - vb) / (nv * nv);
    out[YQ_ELEMS + row] = att * vexp;
  }
}

// ---------------- Kernel Y: pure yQ stream, nontemporal ----------------
// Grid 1024 x 256: 64 rows/block, 256 KB contiguous nt-stores per block.
// NT stores are worth ~40 us here (R8 A/B: plain 104.7 vs NT 64.8) — the
// 268 MB stream otherwise thrashes L2 allocate/evict.
__global__ __launch_bounds__(256) void qac_stream(
    const float* __restrict__ ws, float* __restrict__ out) {
  __shared__ float xis[SROWS];
  const int t = threadIdx.x;
  const int r0 = blockIdx.x * SROWS;
  if (t < SROWS) xis[t] = out[YQ_ELEMS + r0 + t];

  const float4 up = ((const float4*)(ws))[t];
  const float4 un = ((const float4*)(ws + DM))[t];
  const float4 cp = ((const float4*)(ws + 2 * DM))[t];
  const float4 cn = ((const float4*)(ws + 3 * DM))[t];
  __syncthreads();

#pragma unroll 8
  for (int r = 0; r < SROWS; ++r) {
    const float xi = xis[r];
    const bool pos = xi > 0.f;
    floatx4 o;
    o.x = fmaf(xi, pos ? up.x : un.x, pos ? cp.x : cn.x);
    o.y = fmaf(xi, pos ? up.y : un.y, pos ? cp.y : cn.y);
    o.z = fmaf(xi, pos ? up.z : un.z, pos ? cp.z : cn.z);
    o.w = fmaf(xi, pos ? up.w : un.w, pos ? cp.w : cn.w);
    floatx4* dst = (floatx4*)(out + (size_t)(r0 + r) * DM) + t;
    __builtin_nontemporal_store(o, dst);
  }
}

extern "C" void kernel_launch(void* const* d_in, const int* in_sizes, int n_in,
                              void* d_out, int out_size, void* d_ws, size_t ws_size,
                              hipStream_t stream) {
  const float* psiQ = (const float*)d_in[0];
  const float* psiK = (const float*)d_in[1];
  const float* psiV = (const float*)d_in[2];
  const float* W1 = (const float*)d_in[3];
  const float* b1 = (const float*)d_in[4];
  const float* W2 = (const float*)d_in[5];
  const float* b2 = (const float*)d_in[6];
  float* out = (float*)d_out;
  float* ws = (float*)d_ws;

  qac_prep<<<NPBLK + NROWS / XROWS, 256, 0, stream>>>(psiQ, psiK, psiV, W1, b1,
                                                      W2, b2, ws, out);
  qac_stream<<<NROWS / SROWS, 256, 0, stream>>>(ws, out);
}